// Round 8
// baseline (149.906 us; speedup 1.0000x reference)
//
#include <hip/hip_runtime.h>

// AliasFreeActivation fused kernel, v8: plane-pair float2 with splat-uniform
// coefficients (the ONLY packing pattern proven to hit v_pk_fma_f32 rate:
// v4 busy 32us) + half-plane blocks for occupancy (63-row halves -> LDS
// 27984B -> 5 blocks/CU = 20 waves, vs v4's 12) + software-pipelined LDS
// loads (P2 taps loaded one group early; P3 rolling window 2 outputs ahead).
//
// v7 lesson: packed COEFFICIENT pairs need VGPRs (2 different uniforms per
// pair) and blew the launch-bounds cap -> rematerialization bloat. Splat
// coefficients are single-SGPR operands of v_pk_fma_f32 -> zero VGPR cost.
//
// Math identical to v1..v7 (all passed):
//   upH -> (upW + leaky + downW fused) -> downH, crop folded in.
//   hi[l] = sum_t tap[rel+t]*up[c0-4t], rel=((j+5)>>2)-1, c0=20+((j+1)&3)
//   out[o] = sum_k hl[2o+k]*dn[11-k]
// Block = (plane-pair q, half hh). Half hh covers out rows 26hh..26hh+25
// <- t2/tH local rows 0..62 (global 52hh..52hh+62). P2 W-split in 4 segs of
// 13 outputs, seg sample base L0 = 26p-2(p&1) (mult of 4 -> single phase,
// proven in v6). LDS overlay: tH stride 35 (rows<63) then t2 stride 53
// (66 rows incl. read-pad); 66*53*8 = 27984 B.

typedef float v2f __attribute__((ext_vector_type(2)));
static __device__ __forceinline__ v2f vsplat(float s){ v2f v; v.x=s; v.y=s; return v; }
#define FMA2(A,S,C) __builtin_elementwise_fma((A), vsplat(S), (C))

// ---- P2: sample J (local), 6 taps A..F, leaky, scatter into acc2[14] ----
#define SCATTER(J, hv)                                                        \
    _Pragma("unroll")                                                         \
    for (int k = (J) & 1; k <= 11; k += 2) {                                  \
        if ((J) - k >= 0 && (((J) - k) >> 1) < 14)                            \
            acc2[((J) - k) >> 1] = FMA2(hv, dn[11 - k], acc2[((J) - k) >> 1]);\
    }

#define DO_J(J, A, B, C, D, E, F)                                             \
    do {                                                                      \
        const int q_ = ((J) + 1) & 3;                                         \
        v2f h_ = (A) * vsplat(up[20 + q_]);                                   \
        h_ = FMA2((B), up[16 + q_], h_);                                      \
        h_ = FMA2((C), up[12 + q_], h_);                                      \
        h_ = FMA2((D), up[8 + q_], h_);                                       \
        h_ = FMA2((E), up[4 + q_], h_);                                       \
        h_ = FMA2((F), up[q_], h_);                                           \
        h_ = __builtin_elementwise_max(h_, h_ * vsplat(0.2f));                \
        SCATTER(J, h_);                                                       \
    } while (0)

// Group G (samples 4G-1..4G+2, taps G..G+5 = A..F). First issue the load of
// tap G+6 into L (slot of dead tap G-1, L not in A..F) -> consumed only in
// group G+1: ~50 instructions of latency slack.
#define GROUPE(G, L, A, B, C, D, E, F)                                        \
    do {                                                                      \
        L = wbase[(G) + 6];                                                   \
        DO_J(4 * (G) - 1, A, B, C, D, E, F);                                  \
        DO_J(4 * (G),     A, B, C, D, E, F);                                  \
        DO_J(4 * (G) + 1, A, B, C, D, E, F);                                  \
        DO_J(4 * (G) + 2, A, B, C, D, E, F);                                  \
    } while (0)

// ---- P3: output row J from 12 of 16 rolling row-regs ----
#define P3LD(RA, RB, M)                                                       \
    RA = t2b[(M) * 53];                                                       \
    RB = t2b[((M) + 1) * 53];

#define P3OUT(J, A, B, C, D, E, F, G, H, I, JJ, K, L)                         \
    do {                                                                      \
        if (7 * s3 + (J) < 26) {                                              \
            v2f a_ = (A) * vsplat(dn[11]);                                    \
            a_ = FMA2((B), dn[10], a_);                                       \
            a_ = FMA2((C), dn[9], a_);                                        \
            a_ = FMA2((D), dn[8], a_);                                        \
            a_ = FMA2((E), dn[7], a_);                                        \
            a_ = FMA2((F), dn[6], a_);                                        \
            a_ = FMA2((G), dn[5], a_);                                        \
            a_ = FMA2((H), dn[4], a_);                                        \
            a_ = FMA2((I), dn[3], a_);                                        \
            a_ = FMA2((JJ), dn[2], a_);                                       \
            a_ = FMA2((K), dn[1], a_);                                        \
            a_ = FMA2((L), dn[0], a_);                                        \
            const int oh_ = 26 * hh + 7 * s3 + (J);                           \
            op0[oh_ * 52 + ow] = a_.x;                                        \
            op1[oh_ * 52 + ow] = a_.y;                                        \
        }                                                                     \
    } while (0)

__global__ __launch_bounds__(256, 4)
void afa_kernel(const float* __restrict__ x,
                const float* __restrict__ upf,
                const float* __restrict__ dnf,
                float* __restrict__ out)
{
    // Overlay: tH rows (stride 35 v2f, rows 0..62) then t2 (stride 53, 66 rows).
    __shared__ v2f buf[66 * 53];   // 27984 B -> 5 blocks/CU

    const int tid = threadIdx.x;
    const int bid = blockIdx.x;
    const int hh  = bid & 1;                    // H-half: out rows 26hh..26hh+25
    const size_t q0 = (size_t)(bid >> 1) * 2;   // plane pair
    const float* __restrict__ xp0 = x + q0 * 1296;
    const float* __restrict__ xp1 = xp0 + 1296;
    float* __restrict__ op0 = out + q0 * 2704;
    float* __restrict__ op1 = op0 + 2704;

    // filters -> uniform registers (constant-indexed -> SGPRs)
    float up[24];
#pragma unroll
    for (int i = 0; i < 24; ++i) up[i] = upf[i];
    float dn[12];
#pragma unroll
    for (int i = 0; i < 12; ++i) dn[i] = dnf[i];

    // -------- Pass 1: upsample along H, local rows 0..62 (6 segs x 12 rows) --------
    if (tid < 204) {
        const int s1 = tid / 34;        // 0..5
        const int mw = tid % 34 + 1;    // 1..34
        const int xb = 13 * hh + 3 * s1 + 1;    // x row base for this seg

        v2f xr[9];                      // x rows xb .. xb+8 (clamped)
#pragma unroll
        for (int i = 0; i < 9; ++i) {
            int row = xb + i;
            row = row > 35 ? 35 : row;  // clamp; clamped values never used
            xr[i].x = xp0[row * 36 + mw];
            xr[i].y = xp1[row * 36 + mw];
        }
#pragma unroll
        for (int j = 0; j < 12; ++j) {  // lh_loc = 12*s1 + j (global 52hh+lh_loc)
            const int lh = 12 * s1 + j;
            if (lh < 63) {
                const int rel = ((j + 5) >> 2) - 1;   // 0..3, compile-time
                const int c0  = 20 + ((j + 1) & 3);   // compile-time
                v2f a = vsplat(0.f);
#pragma unroll
                for (int t = 0; t < 6; ++t)
                    a = FMA2(xr[rel + t], up[c0 - 4 * t], a);
                buf[lh * 35 + (mw - 1)] = a;          // tH region
            }
        }
    }
    __syncthreads();

    // -------- Pass 2: upW + leaky + downW (4 segs x 13 outputs, single phase) --------
    const int  lh2  = tid % 63;
    const int  p4   = tid / 63;          // 0..3 for tid<252
    const bool act2 = tid < 252;
    v2f acc2[14];
    if (act2) {
        const int L0 = 26 * p4 - ((p4 & 1) << 1);     // 0,24,52,76 (mult of 4)
        const v2f* __restrict__ wbase = &buf[lh2 * 35 + (L0 >> 2)];
        v2f w0 = wbase[0], w1 = wbase[1], w2 = wbase[2],
            w3 = wbase[3], w4 = wbase[4], w5 = wbase[5], w6;
#pragma unroll
        for (int o = 0; o < 14; ++o) acc2[o] = vsplat(0.f);

        w6 = wbase[6];                   // tap 6, consumed first at G=1
        DO_J(0, w0, w1, w2, w3, w4, w5); // taps 0..5
        DO_J(1, w0, w1, w2, w3, w4, w5);
        DO_J(2, w0, w1, w2, w3, w4, w5);
        GROUPE(1, w0, w1, w2, w3, w4, w5, w6);  // taps 1..6; load 7 -> w0
        GROUPE(2, w1, w2, w3, w4, w5, w6, w0);  // taps 2..7; load 8 -> w1
        GROUPE(3, w2, w3, w4, w5, w6, w0, w1);  // taps 3..8; load 9 -> w2
        GROUPE(4, w3, w4, w5, w6, w0, w1, w2);  // taps 4..9; load 10 -> w3
        GROUPE(5, w4, w5, w6, w0, w1, w2, w3);  // taps 5..10; load 11 -> w4
        GROUPE(6, w5, w6, w0, w1, w2, w3, w4);  // taps 6..11; load 12 -> w5
        GROUPE(7, w6, w0, w1, w2, w3, w4, w5);  // taps 7..12; load 13 -> w6
        GROUPE(8, w0, w1, w2, w3, w4, w5, w6);  // taps 8..13; load 14 -> w0
        DO_J(35, w2, w3, w4, w5, w6, w0);       // taps 9..14
        DO_J(36, w2, w3, w4, w5, w6, w0);
        DO_J(37, w2, w3, w4, w5, w6, w0);
    }
    __syncthreads();   // all tH reads complete before any t2 write (overlay)

    if (act2) {
        v2f* __restrict__ tw = &buf[lh2 * 53 + 13 * p4];   // t2 region
        if (p4 & 1) {
#pragma unroll
            for (int oo = 0; oo < 13; ++oo) tw[oo] = acc2[oo + 1];
        } else {
#pragma unroll
            for (int oo = 0; oo < 13; ++oo) tw[oo] = acc2[oo];
        }
    }
    __syncthreads();

    // -------- Pass 3: downsample along H (4 segs x <=7 rows), rolling window --------
    if (tid < 208) {
        const int ow = tid % 52;
        const int s3 = tid / 52;         // 0..3; out local rows 7s3.. (guarded <26)
        const v2f* __restrict__ t2b = &buf[(14 * s3) * 53 + ow];

        v2f r0, r1, r2, r3, r4, r5, r6, r7, r8, r9, r10, r11, r12, r13, r14, r15;
        P3LD(r0, r1, 0)   P3LD(r2, r3, 2)   P3LD(r4, r5, 4)
        P3LD(r6, r7, 6)   P3LD(r8, r9, 8)   P3LD(r10, r11, 10)
        P3LD(r12, r13, 12)                  // rows 0..13 preloaded

        P3LD(r14, r15, 14)                  // rows 14,15 (used at out2)
        P3OUT(0, r0, r1, r2, r3, r4, r5, r6, r7, r8, r9, r10, r11);
        P3LD(r0, r1, 16)                    // rows 16,17 (used at out3)
        P3OUT(1, r2, r3, r4, r5, r6, r7, r8, r9, r10, r11, r12, r13);
        P3LD(r2, r3, 18)
        P3OUT(2, r4, r5, r6, r7, r8, r9, r10, r11, r12, r13, r14, r15);
        P3LD(r4, r5, 20)
        P3OUT(3, r6, r7, r8, r9, r10, r11, r12, r13, r14, r15, r0, r1);
        P3LD(r6, r7, 22)                    // rows 22,23 (max LDS row 14*3+23=65)
        P3OUT(4, r8, r9, r10, r11, r12, r13, r14, r15, r0, r1, r2, r3);
        P3OUT(5, r10, r11, r12, r13, r14, r15, r0, r1, r2, r3, r4, r5);
        P3OUT(6, r12, r13, r14, r15, r0, r1, r2, r3, r4, r5, r6, r7);
    }
}

extern "C" void kernel_launch(void* const* d_in, const int* in_sizes, int n_in,
                              void* d_out, int out_size, void* d_ws, size_t ws_size,
                              hipStream_t stream)
{
    const float* x  = (const float*)d_in[0];   // (16,512,36,36)
    const float* up = (const float*)d_in[1];   // (24,)
    const float* dn = (const float*)d_in[2];   // (12,)
    float* out = (float*)d_out;                // (16,512,52,52)

    // 4096 plane-pairs x 2 H-halves; consecutive blocks share x rows (L2 reuse)
    afa_kernel<<<dim3(16 * 512 / 2 * 2), dim3(256), 0, stream>>>(x, up, dn, out);
}